// Round 14
// baseline (744.514 us; speedup 1.0000x reference)
//
#include <hip/hip_runtime.h>

#define E_CNT 200000
#define N_CNT 50000
#define CS_PARTS 128

typedef __attribute__((ext_vector_type(8))) unsigned short ushort8;
typedef __attribute__((ext_vector_type(4))) unsigned short us4;
typedef __attribute__((ext_vector_type(4))) float f32x4;
typedef __bf16 bf16x8 __attribute__((ext_vector_type(8)));

static __device__ __forceinline__ unsigned short f2bf(float f) {
  unsigned int u = __builtin_bit_cast(unsigned int, f);
  u += 0x7FFFu + ((u >> 16) & 1u);
  return (unsigned short)(u >> 16);
}
static __device__ __forceinline__ float bf2f(unsigned short u) {
  unsigned int x = ((unsigned int)u) << 16;
  return __builtin_bit_cast(float, x);
}

// ---------- dispatch 1: weight prep + cvec + hist ----------
// blocks 0..159: frag-ready bf16 W conversion (5 subs x 32)
// blocks 160/161: ce / cn ; blocks 162..943: hist of receivers
__global__ void prep_hist(const float* __restrict__ We, const float* __restrict__ be,
                          const float* __restrict__ Wn, const float* __restrict__ bn,
                          const float* __restrict__ g, const int* __restrict__ recv,
                          unsigned short* __restrict__ BpEe, unsigned short* __restrict__ BpPs,
                          unsigned short* __restrict__ BpPr, unsigned short* __restrict__ BpNe,
                          unsigned short* __restrict__ BpPn, float* __restrict__ ce,
                          float* __restrict__ cn, int* __restrict__ count) {
  int bid = blockIdx.x;
  if (bid >= 162) {
    int e = (bid - 162) * 256 + threadIdx.x;
    if (e < E_CNT) atomicAdd(&count[recv[e]], 1);
    return;
  }
  if (bid >= 160) {
    int j = threadIdx.x;  // 256
    if (bid == 160) {
      float s = be[j];
      for (int k = 0; k < 128; ++k) s += g[k] * We[(size_t)(768 + k) * 256 + j];
      ce[j] = s;
    } else {
      float s = bn[j];
      for (int k = 0; k < 128; ++k) s += g[k] * Wn[(size_t)(512 + k) * 256 + j];
      cn[j] = s;
    }
    return;
  }
  int sub = bid >> 5;
  const float* W;
  unsigned short* Bp;
  if (sub == 0)      { W = We;           Bp = BpEe; }
  else if (sub == 1) { W = We + 65536;   Bp = BpPs; }
  else if (sub == 2) { W = We + 131072;  Bp = BpPr; }
  else if (sub == 3) { W = Wn;           Bp = BpNe; }
  else               { W = Wn + 65536;   Bp = BpPn; }
  int idx = (bid & 31) * 256 + threadIdx.x;  // 0..8191 (KC=8)
  int lane = idx & 63;
  int t = idx >> 6;
  int F = t & 15;
  int kc = t >> 4;
  int col = F * 16 + (lane & 15);
  int kb = kc * 32 + (lane >> 4) * 8;
  ushort8 v;
#pragma unroll
  for (int j = 0; j < 8; ++j) v[j] = f2bf(W[(size_t)(kb + j) * 256 + col]);
  *reinterpret_cast<ushort8*>(Bp + (size_t)idx * 8) = v;
}

// ---------- dispatch 2: exclusive scan ----------
__global__ __launch_bounds__(1024) void scan_build(const int* __restrict__ count,
                                                   int* __restrict__ offs,
                                                   int* __restrict__ cursor) {
  __shared__ int part[1024];
  const int t = threadIdx.x;
  const int CH = 49;  // 1024*49 >= 50000
  const int base = t * CH;
  int s = 0;
  for (int i = 0; i < CH; ++i) {
    int idx = base + i;
    if (idx < N_CNT) s += count[idx];
  }
  part[t] = s;
  __syncthreads();
  for (int d = 1; d < 1024; d <<= 1) {
    int v = (t >= d) ? part[t - d] : 0;
    __syncthreads();
    part[t] += v;
    __syncthreads();
  }
  int run = (t == 0) ? 0 : part[t - 1];
  for (int i = 0; i < CH; ++i) {
    int idx = base + i;
    if (idx < N_CNT) {
      offs[idx] = run;
      cursor[idx] = run;
      run += count[idx];
    }
  }
  if (t == 1023) offs[N_CNT] = run;  // == E_CNT
}

// ---------- dispatch 3: tri-projection (A staged once) + scatter ----------
// blocks 0..nbN-1: Ps = nodes@We_s, Pr = nodes@We_r, Pn = nodes@Wn_v
//   (bf16 slot layout: slot = wn*64 + lr*4 + fn)
// blocks nbN.. : scatter edges into receiver-sorted order
__global__ __launch_bounds__(512, 4) void proj3_scatter(
    const float* __restrict__ nodes, const unsigned short* __restrict__ BpPs,
    const unsigned short* __restrict__ BpPr, const unsigned short* __restrict__ BpPn,
    const int* __restrict__ recv, int* __restrict__ cursor, int* __restrict__ eord,
    unsigned short* __restrict__ Ps, unsigned short* __restrict__ Pr,
    unsigned short* __restrict__ Pn, int nbN) {
  if (blockIdx.x >= nbN) {
    int e = (blockIdx.x - nbN) * 512 + threadIdx.x;
    if (e < E_CNT) {
      int pos = atomicAdd(&cursor[recv[e]], 1);
      eord[pos] = e;
    }
    return;
  }
  __shared__ unsigned short ldsA[4][64 * 64];  // 32 KB: whole 64x256 A tile

  const int tid = threadIdx.x;
  const int lane = tid & 63;
  const int wave = tid >> 6;
  const int wm = wave >> 2;
  const int wn = wave & 3;
  const int q = lane >> 4;
  const int lr = lane & 15;
  const int row0 = blockIdx.x * 64;

  const int sr = tid >> 3;
  const int sc = tid & 7;
  int er = row0 + sr;
  if (er > N_CNT - 1) er = N_CNT - 1;
  const float* sbase = nodes + (size_t)er * 256;
  const int swz = sr & 7;
  const int wbase = sr * 64;
  const int s0 = (sc ^ swz) * 8;

  // stage the full K=256 tile once
#pragma unroll
  for (int ks = 0; ks < 4; ++ks) {
    f32x4 f0 = *reinterpret_cast<const f32x4*>(sbase + ks * 64 + sc * 8);
    f32x4 f1 = *reinterpret_cast<const f32x4*>(sbase + ks * 64 + sc * 8 + 4);
    ushort8 w0;
#pragma unroll
    for (int j = 0; j < 4; ++j) {
      w0[j] = f2bf(f0[j]);
      w0[4 + j] = f2bf(f1[j]);
    }
    *reinterpret_cast<ushort8*>(&ldsA[ks][wbase + s0]) = w0;
  }
  __syncthreads();

  auto do_proj = [&](const unsigned short* __restrict__ Bp,
                     unsigned short* __restrict__ outP) {
    f32x4 acc[2][4] = {};
#pragma unroll
    for (int ks = 0; ks < 4; ++ks) {
#pragma unroll
      for (int kk = 0; kk < 2; ++kk) {
        const int kc32 = ks * 2 + kk;
        bf16x8 bfr[4];
#pragma unroll
        for (int fn = 0; fn < 4; ++fn) {
          const int F = wn * 4 + fn;
          bfr[fn] = __builtin_bit_cast(
              bf16x8, *reinterpret_cast<const ushort8*>(
                          Bp + ((size_t)(kc32 * 16 + F) * 64 + lane) * 8));
        }
        bf16x8 a[2];
#pragma unroll
        for (int fm = 0; fm < 2; ++fm) {
          int r = wm * 32 + fm * 16 + lr;
          int slot = (kk * 4 + q) ^ (r & 7);
          a[fm] = __builtin_bit_cast(
              bf16x8, *reinterpret_cast<const ushort8*>(&ldsA[ks][r * 64 + slot * 8]));
        }
#pragma unroll
        for (int fm = 0; fm < 2; ++fm)
#pragma unroll
          for (int fn = 0; fn < 4; ++fn)
            acc[fm][fn] = __builtin_amdgcn_mfma_f32_16x16x32_bf16(
                a[fm], bfr[fn], acc[fm][fn], 0, 0, 0);
      }
    }
#pragma unroll
    for (int fm = 0; fm < 2; ++fm) {
      int rb = row0 + wm * 32 + fm * 16 + q * 4;
#pragma unroll
      for (int i = 0; i < 4; ++i) {
        int gr = rb + i;
        if (gr < N_CNT) {
          us4 pv;
#pragma unroll
          for (int fn = 0; fn < 4; ++fn) pv[fn] = f2bf(acc[fm][fn][i]);
          *reinterpret_cast<us4*>(outP + (size_t)gr * 256 + wn * 64 + lr * 4) = pv;
        }
      }
    }
  };

  do_proj(BpPs, Ps);
  do_proj(BpPr, Pr);
  do_proj(BpPn, Pn);
}

// ---------- dispatch 4: edge GEMM (no atomics, plain stores) ----------
// v = relu(edges@We_e + ce + Ps[snd] + Pr[rcv]); store out0; colsum -> partE
__global__ __launch_bounds__(512, 8) void edge_gemm(
    const float* __restrict__ edges, const unsigned short* __restrict__ BpEe,
    const unsigned short* __restrict__ Ps, const unsigned short* __restrict__ Pr,
    const float* __restrict__ ce, const int* __restrict__ senders,
    const int* __restrict__ receivers, float* __restrict__ out0,
    float* __restrict__ partE) {
  __shared__ unsigned short lds[2][64 * 64];

  const int tid = threadIdx.x;
  const int lane = tid & 63;
  const int wave = tid >> 6;
  const int wm = wave >> 2;
  const int wn = wave & 3;
  const int q = lane >> 4;
  const int lr = lane & 15;
  const int row0 = blockIdx.x * 64;

  const int sr = tid >> 3;
  const int sc = tid & 7;
  const int er = row0 + sr;  // grid covers E exactly
  const float* sbase = edges + (size_t)er * 256;
  const int swz = sr & 7;
  const int wbase = sr * 64;
  const int s0 = (sc ^ swz) * 8;

  f32x4 acc[2][4] = {};

  {
    f32x4 f0 = *reinterpret_cast<const f32x4*>(sbase + sc * 8);
    f32x4 f1 = *reinterpret_cast<const f32x4*>(sbase + sc * 8 + 4);
    ushort8 w0;
#pragma unroll
    for (int j = 0; j < 4; ++j) {
      w0[j] = f2bf(f0[j]);
      w0[4 + j] = f2bf(f1[j]);
    }
    *reinterpret_cast<ushort8*>(&lds[0][wbase + s0]) = w0;
  }
  __syncthreads();

#pragma unroll
  for (int ks = 0; ks < 4; ++ks) {
    const int cc = ks & 1;
    f32x4 nf0, nf1;
    if (ks + 1 < 4) {
      nf0 = *reinterpret_cast<const f32x4*>(sbase + (ks + 1) * 64 + sc * 8);
      nf1 = *reinterpret_cast<const f32x4*>(sbase + (ks + 1) * 64 + sc * 8 + 4);
    }

#pragma unroll
    for (int kk = 0; kk < 2; ++kk) {
      const int kc32 = ks * 2 + kk;
      bf16x8 bfr[4];
#pragma unroll
      for (int fn = 0; fn < 4; ++fn) {
        const int F = wn * 4 + fn;
        bfr[fn] = __builtin_bit_cast(
            bf16x8, *reinterpret_cast<const ushort8*>(
                        BpEe + ((size_t)(kc32 * 16 + F) * 64 + lane) * 8));
      }
      bf16x8 a[2];
#pragma unroll
      for (int fm = 0; fm < 2; ++fm) {
        int r = wm * 32 + fm * 16 + lr;
        int slot = (kk * 4 + q) ^ (r & 7);
        a[fm] = __builtin_bit_cast(
            bf16x8, *reinterpret_cast<const ushort8*>(&lds[cc][r * 64 + slot * 8]));
      }
#pragma unroll
      for (int fm = 0; fm < 2; ++fm)
#pragma unroll
        for (int fn = 0; fn < 4; ++fn)
          acc[fm][fn] = __builtin_amdgcn_mfma_f32_16x16x32_bf16(
              a[fm], bfr[fn], acc[fm][fn], 0, 0, 0);
    }

    if (ks + 1 < 4) {
      ushort8 w0;
#pragma unroll
      for (int j = 0; j < 4; ++j) {
        w0[j] = f2bf(nf0[j]);
        w0[4 + j] = f2bf(nf1[j]);
      }
      *reinterpret_cast<ushort8*>(&lds[cc ^ 1][wbase + s0]) = w0;
      __syncthreads();
    }
  }

  float bcol[4];
#pragma unroll
  for (int fn = 0; fn < 4; ++fn) bcol[fn] = ce[wn * 64 + fn * 16 + lr];
  float cs[4] = {0.f, 0.f, 0.f, 0.f};

#pragma unroll
  for (int fm = 0; fm < 2; ++fm) {
    int rb = row0 + wm * 32 + fm * 16 + q * 4;
#pragma unroll
    for (int i = 0; i < 4; ++i) {
      int gr = rb + i;
      int snd = senders[gr], rcv = receivers[gr];
      us4 ps = *reinterpret_cast<const us4*>(Ps + (size_t)snd * 256 + wn * 64 + lr * 4);
      us4 pr = *reinterpret_cast<const us4*>(Pr + (size_t)rcv * 256 + wn * 64 + lr * 4);
#pragma unroll
      for (int fn = 0; fn < 4; ++fn) {
        int col = wn * 64 + fn * 16 + lr;
        float v = fmaxf(acc[fm][fn][i] + bcol[fn] + bf2f(ps[fn]) + bf2f(pr[fn]), 0.0f);
        cs[fn] += v;
        out0[(size_t)gr * 256 + col] = v;  // plain store: L2/L3-warm for node gather
      }
    }
  }

  // fused column sum -> partE
  float* csum = reinterpret_cast<float*>(&lds[0][0]);
  __syncthreads();
  if (tid < 256) csum[tid] = 0.f;
  __syncthreads();
#pragma unroll
  for (int fn = 0; fn < 4; ++fn) atomicAdd(&csum[wn * 64 + fn * 16 + lr], cs[fn]);
  __syncthreads();
  if (tid < 256)
    atomicAdd(&partE[(size_t)(blockIdx.x & (CS_PARTS - 1)) * 256 + tid], csum[tid]);
}

// ---------- dispatch 5: node GEMM (CSR gather staging) + esum reduce ----------
// block nbN: esum = colsum_p2(partE). blocks 0..nbN-1:
// A row n = sum_{j in [offs[n],offs[n+1])} out0[eord[j]];
// v = relu(A@Wn_e + Pn[n] + cn); store out1; colsum -> partN
__global__ __launch_bounds__(512, 6) void node_gemm(
    const float* __restrict__ out0, const unsigned short* __restrict__ BpNe,
    const unsigned short* __restrict__ Pn, const float* __restrict__ cn,
    const int* __restrict__ offs, const int* __restrict__ eord,
    const float* __restrict__ partE, float* __restrict__ esum,
    float* __restrict__ out1, float* __restrict__ partN, int nbN) {
  if (blockIdx.x >= nbN) {
    int c = threadIdx.x;
    if (c < 256) {
      float s = 0.f;
      for (int p = 0; p < CS_PARTS; ++p) s += partE[(size_t)p * 256 + c];
      esum[c] = s;
    }
    return;
  }
  __shared__ unsigned short ldsA[4][64 * 64];  // 32 KB: whole agg tile

  const int tid = threadIdx.x;
  const int lane = tid & 63;
  const int wave = tid >> 6;
  const int wm = wave >> 2;
  const int wn = wave & 3;
  const int q = lane >> 4;
  const int lr = lane & 15;
  const int row0 = blockIdx.x * 64;

  const int sr = tid >> 3;
  const int sc = tid & 7;
  int er = row0 + sr;
  if (er > N_CNT - 1) er = N_CNT - 1;
  const int o0 = offs[er], o1 = offs[er + 1];
  const int swz = sr & 7;
  const int wbase = sr * 64;
  const int s0 = (sc ^ swz) * 8;

  // gather-sum the full agg row (8 x f32x4 accumulators), then stage
  {
    f32x4 r0 = {0.f, 0.f, 0.f, 0.f}, r1 = r0, r2 = r0, r3 = r0;
    f32x4 r4 = r0, r5 = r0, r6 = r0, r7 = r0;
    for (int j = o0; j < o1; ++j) {
      const float* p = out0 + (size_t)eord[j] * 256 + sc * 8;
      r0 += *reinterpret_cast<const f32x4*>(p);
      r1 += *reinterpret_cast<const f32x4*>(p + 4);
      r2 += *reinterpret_cast<const f32x4*>(p + 64);
      r3 += *reinterpret_cast<const f32x4*>(p + 68);
      r4 += *reinterpret_cast<const f32x4*>(p + 128);
      r5 += *reinterpret_cast<const f32x4*>(p + 132);
      r6 += *reinterpret_cast<const f32x4*>(p + 192);
      r7 += *reinterpret_cast<const f32x4*>(p + 196);
    }
    f32x4 lo[4] = {r0, r2, r4, r6};
    f32x4 hi[4] = {r1, r3, r5, r7};
#pragma unroll
    for (int ks = 0; ks < 4; ++ks) {
      ushort8 w0;
#pragma unroll
      for (int j = 0; j < 4; ++j) {
        w0[j] = f2bf(lo[ks][j]);
        w0[4 + j] = f2bf(hi[ks][j]);
      }
      *reinterpret_cast<ushort8*>(&ldsA[ks][wbase + s0]) = w0;
    }
  }
  __syncthreads();

  f32x4 acc[2][4] = {};
#pragma unroll
  for (int ks = 0; ks < 4; ++ks) {
#pragma unroll
    for (int kk = 0; kk < 2; ++kk) {
      const int kc32 = ks * 2 + kk;
      bf16x8 bfr[4];
#pragma unroll
      for (int fn = 0; fn < 4; ++fn) {
        const int F = wn * 4 + fn;
        bfr[fn] = __builtin_bit_cast(
            bf16x8, *reinterpret_cast<const ushort8*>(
                        BpNe + ((size_t)(kc32 * 16 + F) * 64 + lane) * 8));
      }
      bf16x8 a[2];
#pragma unroll
      for (int fm = 0; fm < 2; ++fm) {
        int r = wm * 32 + fm * 16 + lr;
        int slot = (kk * 4 + q) ^ (r & 7);
        a[fm] = __builtin_bit_cast(
            bf16x8, *reinterpret_cast<const ushort8*>(&ldsA[ks][r * 64 + slot * 8]));
      }
#pragma unroll
      for (int fm = 0; fm < 2; ++fm)
#pragma unroll
        for (int fn = 0; fn < 4; ++fn)
          acc[fm][fn] = __builtin_amdgcn_mfma_f32_16x16x32_bf16(
              a[fm], bfr[fn], acc[fm][fn], 0, 0, 0);
    }
  }

  float bcol[4];
#pragma unroll
  for (int fn = 0; fn < 4; ++fn) bcol[fn] = cn[wn * 64 + fn * 16 + lr];
  float cs[4] = {0.f, 0.f, 0.f, 0.f};

#pragma unroll
  for (int fm = 0; fm < 2; ++fm) {
    int rb = row0 + wm * 32 + fm * 16 + q * 4;
#pragma unroll
    for (int i = 0; i < 4; ++i) {
      int gr = rb + i;
      if (gr < N_CNT) {
        us4 pn = *reinterpret_cast<const us4*>(Pn + (size_t)gr * 256 + wn * 64 + lr * 4);
#pragma unroll
        for (int fn = 0; fn < 4; ++fn) {
          int col = wn * 64 + fn * 16 + lr;
          float v = fmaxf(acc[fm][fn][i] + bcol[fn] + bf2f(pn[fn]), 0.0f);
          cs[fn] += v;
          out1[(size_t)gr * 256 + col] = v;
        }
      }
    }
  }

  // fused column sum -> partN
  float* csum = reinterpret_cast<float*>(&ldsA[0][0]);
  __syncthreads();
  if (tid < 256) csum[tid] = 0.f;
  __syncthreads();
#pragma unroll
  for (int fn = 0; fn < 4; ++fn) atomicAdd(&csum[wn * 64 + fn * 16 + lr], cs[fn]);
  __syncthreads();
  if (tid < 256)
    atomicAdd(&partN[(size_t)(blockIdx.x & (CS_PARTS - 1)) * 256 + tid], csum[tid]);
}

// ---------- dispatch 6: nsum reduce + global MLP ----------
__global__ void finalize(const float* __restrict__ partN, const float* __restrict__ esum,
                         const float* __restrict__ gl, const float* __restrict__ Wg,
                         const float* __restrict__ bg, float* __restrict__ out2) {
  __shared__ float ns[256];
  __shared__ float red[512];
  int t = threadIdx.x;  // 512
  if (t < 256) {
    float s = 0.f;
    for (int p = 0; p < CS_PARTS; ++p) s += partN[(size_t)p * 256 + t];
    ns[t] = s;
  }
  __syncthreads();
  int g = t & 127;
  int kg = t >> 7;
  float acc = 0.f;
  for (int k = kg; k < 640; k += 4) {
    float x = (k < 256) ? esum[k] : (k < 512 ? ns[k - 256] : gl[k - 512]);
    acc += x * Wg[(size_t)k * 128 + g];
  }
  red[t] = acc;
  __syncthreads();
  if (kg == 0) {
    float r = red[g] + red[128 + g] + red[256 + g] + red[384 + g] + bg[g];
    out2[g] = fmaxf(r, 0.f);
  }
}

extern "C" void kernel_launch(void* const* d_in, const int* in_sizes, int n_in,
                              void* d_out, int out_size, void* d_ws, size_t ws_size,
                              hipStream_t stream) {
  const float* nodes = (const float*)d_in[0];
  const float* edges = (const float*)d_in[1];
  const float* gl = (const float*)d_in[2];
  const int* senders = (const int*)d_in[3];
  const int* receivers = (const int*)d_in[4];
  const float* We = (const float*)d_in[5];
  const float* be = (const float*)d_in[6];
  const float* Wn = (const float*)d_in[7];
  const float* bn = (const float*)d_in[8];
  const float* Wg = (const float*)d_in[9];
  const float* bg = (const float*)d_in[10];

  float* out0 = (float*)d_out;               // new_edges [200000,256]
  float* out1 = out0 + (size_t)E_CNT * 256;  // new_nodes [50000,256]
  float* out2 = out1 + (size_t)N_CNT * 256;  // new_globals [128]

  char* ws = (char*)d_ws;
  size_t o = 0;
  int* count = (int*)(ws + o);                      o += 200704;
  float* partE = (float*)(ws + o);                  o += CS_PARTS * 256 * 4;
  float* partN = (float*)(ws + o);                  o += CS_PARTS * 256 * 4;
  size_t zeroBytes = o;  // count + partE + partN in one memset
  int* offs = (int*)(ws + o);                       o += 200704;  // N_CNT+1
  int* cursor = (int*)(ws + o);                     o += 200704;
  int* eord = (int*)(ws + o);                       o += 800000;
  unsigned short* Ps = (unsigned short*)(ws + o);   o += (size_t)N_CNT * 256 * 2;
  unsigned short* Pr = (unsigned short*)(ws + o);   o += (size_t)N_CNT * 256 * 2;
  unsigned short* Pn = (unsigned short*)(ws + o);   o += (size_t)N_CNT * 256 * 2;
  unsigned short* BpEe = (unsigned short*)(ws + o); o += 131072;
  unsigned short* BpPs = (unsigned short*)(ws + o); o += 131072;
  unsigned short* BpPr = (unsigned short*)(ws + o); o += 131072;
  unsigned short* BpNe = (unsigned short*)(ws + o); o += 131072;
  unsigned short* BpPn = (unsigned short*)(ws + o); o += 131072;
  float* ce = (float*)(ws + o);                     o += 1024;
  float* cn = (float*)(ws + o);                     o += 1024;
  float* esum = (float*)(ws + o);                   o += 1024;

  hipMemsetAsync(ws, 0, zeroBytes, stream);

  prep_hist<<<944, 256, 0, stream>>>(We, be, Wn, bn, gl, receivers, BpEe, BpPs,
                                     BpPr, BpNe, BpPn, ce, cn, count);

  scan_build<<<1, 1024, 0, stream>>>(count, offs, cursor);

  const int nbN = (N_CNT + 63) / 64;  // 782
  proj3_scatter<<<nbN + (E_CNT + 511) / 512, 512, 0, stream>>>(
      nodes, BpPs, BpPr, BpPn, receivers, cursor, eord, Ps, Pr, Pn, nbN);

  edge_gemm<<<E_CNT / 64, 512, 0, stream>>>(edges, BpEe, Ps, Pr, ce, senders,
                                            receivers, out0, partE);

  node_gemm<<<nbN + 1, 512, 0, stream>>>(out0, BpNe, Pn, cn, offs, eord, partE,
                                         esum, out1, partN, nbN);

  finalize<<<1, 512, 0, stream>>>(partN, esum, gl, Wg, bg, out2);
}

// Round 15
// 473.712 us; speedup vs baseline: 1.5717x; 1.5717x over previous
//
#include <hip/hip_runtime.h>

#define E_CNT 200000
#define N_CNT 50000
#define CS_PARTS 128

typedef __attribute__((ext_vector_type(8))) unsigned short ushort8;
typedef __attribute__((ext_vector_type(4))) unsigned short us4;
typedef __attribute__((ext_vector_type(4))) float f32x4;
typedef __bf16 bf16x8 __attribute__((ext_vector_type(8)));

static __device__ __forceinline__ unsigned short f2bf(float f) {
  unsigned int u = __builtin_bit_cast(unsigned int, f);
  u += 0x7FFFu + ((u >> 16) & 1u);
  return (unsigned short)(u >> 16);
}
static __device__ __forceinline__ float bf2f(unsigned short u) {
  unsigned int x = ((unsigned int)u) << 16;
  return __builtin_bit_cast(float, x);
}

// ---------- dispatch 1: weight prep + cvec ----------
// blocks 0..159: frag-ready bf16 W conversion (5 subs x 32):
//   sub0 We_e->BpEe  sub1 We_s->BpPs  sub2 We_r->BpPr
//   sub3 Wn_e->BpN[0:8)  sub4 Wn_v->BpN[8:16)
// blocks 160/161: ce = be + g@We_g ; cn = bn + g@Wn_g
__global__ void prep_all(const float* __restrict__ We, const float* __restrict__ be,
                         const float* __restrict__ Wn, const float* __restrict__ bn,
                         const float* __restrict__ g, unsigned short* __restrict__ BpEe,
                         unsigned short* __restrict__ BpPs, unsigned short* __restrict__ BpPr,
                         unsigned short* __restrict__ BpN, float* __restrict__ ce,
                         float* __restrict__ cn) {
  int bid = blockIdx.x;
  if (bid >= 160) {
    int j = threadIdx.x;  // 256
    if (bid == 160) {
      float s = be[j];
      for (int k = 0; k < 128; ++k) s += g[k] * We[(size_t)(768 + k) * 256 + j];
      ce[j] = s;
    } else {
      float s = bn[j];
      for (int k = 0; k < 128; ++k) s += g[k] * Wn[(size_t)(512 + k) * 256 + j];
      cn[j] = s;
    }
    return;
  }
  int sub = bid >> 5;
  const float* W;
  unsigned short* Bp;
  if (sub == 0)      { W = We;           Bp = BpEe; }
  else if (sub == 1) { W = We + 65536;   Bp = BpPs; }
  else if (sub == 2) { W = We + 131072;  Bp = BpPr; }
  else if (sub == 3) { W = Wn;           Bp = BpN; }
  else               { W = Wn + 65536;   Bp = BpN + 65536; }
  int idx = (bid & 31) * 256 + threadIdx.x;  // 0..8191 (KC=8)
  int lane = idx & 63;
  int t = idx >> 6;
  int F = t & 15;
  int kc = t >> 4;
  int col = F * 16 + (lane & 15);
  int kb = kc * 32 + (lane >> 4) * 8;
  ushort8 v;
#pragma unroll
  for (int j = 0; j < 8; ++j) v[j] = f2bf(W[(size_t)(kb + j) * 256 + col]);
  *reinterpret_cast<ushort8*>(Bp + (size_t)idx * 8) = v;
}

// ---------- dispatch 2: bi-projection, A staged once ----------
// Ps = nodes@We_s, Pr = nodes@We_r ; bf16 slot layout slot = wn*64 + lr*4 + fn
__global__ __launch_bounds__(512, 4) void proj2(
    const float* __restrict__ nodes, const unsigned short* __restrict__ BpPs,
    const unsigned short* __restrict__ BpPr, unsigned short* __restrict__ Ps,
    unsigned short* __restrict__ Pr) {
  __shared__ unsigned short ldsA[4][64 * 64];  // 32 KB: whole 64x256 A tile

  const int tid = threadIdx.x;
  const int lane = tid & 63;
  const int wave = tid >> 6;
  const int wm = wave >> 2;
  const int wn = wave & 3;
  const int q = lane >> 4;
  const int lr = lane & 15;
  const int row0 = blockIdx.x * 64;

  const int sr = tid >> 3;
  const int sc = tid & 7;
  int er = row0 + sr;
  if (er > N_CNT - 1) er = N_CNT - 1;
  const float* sbase = nodes + (size_t)er * 256;
  const int swz = sr & 7;
  const int wbase = sr * 64;
  const int s0 = (sc ^ swz) * 8;

#pragma unroll
  for (int ks = 0; ks < 4; ++ks) {
    f32x4 f0 = *reinterpret_cast<const f32x4*>(sbase + ks * 64 + sc * 8);
    f32x4 f1 = *reinterpret_cast<const f32x4*>(sbase + ks * 64 + sc * 8 + 4);
    ushort8 w0;
#pragma unroll
    for (int j = 0; j < 4; ++j) {
      w0[j] = f2bf(f0[j]);
      w0[4 + j] = f2bf(f1[j]);
    }
    *reinterpret_cast<ushort8*>(&ldsA[ks][wbase + s0]) = w0;
  }
  __syncthreads();

  auto do_proj = [&](const unsigned short* __restrict__ Bp,
                     unsigned short* __restrict__ outP) {
    f32x4 acc[2][4] = {};
#pragma unroll
    for (int ks = 0; ks < 4; ++ks) {
#pragma unroll
      for (int kk = 0; kk < 2; ++kk) {
        const int kc32 = ks * 2 + kk;
        bf16x8 bfr[4];
#pragma unroll
        for (int fn = 0; fn < 4; ++fn) {
          const int F = wn * 4 + fn;
          bfr[fn] = __builtin_bit_cast(
              bf16x8, *reinterpret_cast<const ushort8*>(
                          Bp + ((size_t)(kc32 * 16 + F) * 64 + lane) * 8));
        }
        bf16x8 a[2];
#pragma unroll
        for (int fm = 0; fm < 2; ++fm) {
          int r = wm * 32 + fm * 16 + lr;
          int slot = (kk * 4 + q) ^ (r & 7);
          a[fm] = __builtin_bit_cast(
              bf16x8, *reinterpret_cast<const ushort8*>(&ldsA[ks][r * 64 + slot * 8]));
        }
#pragma unroll
        for (int fm = 0; fm < 2; ++fm)
#pragma unroll
          for (int fn = 0; fn < 4; ++fn)
            acc[fm][fn] = __builtin_amdgcn_mfma_f32_16x16x32_bf16(
                a[fm], bfr[fn], acc[fm][fn], 0, 0, 0);
      }
    }
#pragma unroll
    for (int fm = 0; fm < 2; ++fm) {
      int rb = row0 + wm * 32 + fm * 16 + q * 4;
#pragma unroll
      for (int i = 0; i < 4; ++i) {
        int gr = rb + i;
        if (gr < N_CNT) {
          us4 pv;
#pragma unroll
          for (int fn = 0; fn < 4; ++fn) pv[fn] = f2bf(acc[fm][fn][i]);
          *reinterpret_cast<us4*>(outP + (size_t)gr * 256 + wn * 64 + lr * 4) = pv;
        }
      }
    }
  };

  do_proj(BpPs, Ps);
  do_proj(BpPr, Pr);
}

// ---------- dispatch 3: edge GEMM (R7 128-tile config, fused atomics) ----------
// v = relu(edges@We_e + ce + Ps[snd] + Pr[rcv]); nt-store out0;
// f32 atomicAdd agg[rcv]; fused colsum -> partE
__global__ __launch_bounds__(512, 2) void edge_gemm(
    const float* __restrict__ edges, const unsigned short* __restrict__ BpEe,
    const unsigned short* __restrict__ Ps, const unsigned short* __restrict__ Pr,
    const float* __restrict__ ce, const int* __restrict__ senders,
    const int* __restrict__ receivers, float* __restrict__ out0,
    float* __restrict__ agg, float* __restrict__ partE) {
  __shared__ unsigned short lds[2][128 * 64];  // 32 KB double-buffered A

  const int tid = threadIdx.x;
  const int lane = tid & 63;
  const int wave = tid >> 6;
  const int wm = wave >> 2;   // 0..1 : 64-row half
  const int wn = wave & 3;    // 0..3 : 64-col quarter
  const int q = lane >> 4;
  const int lr = lane & 15;
  const int row0 = blockIdx.x * 128;

  const int sr = tid >> 2;  // 0..127
  const int sc = tid & 3;   // 16-float chunk
  int er = row0 + sr;
  if (er > E_CNT - 1) er = E_CNT - 1;
  const float* sbase = edges + (size_t)er * 256;

  const int swz = sr & 7;
  const int wbase = sr * 64;
  const int s0 = ((sc * 2) ^ swz) * 8;
  const int s1 = ((sc * 2 + 1) ^ swz) * 8;

  f32x4 acc[4][4] = {};

  {
    const float4* p4 = reinterpret_cast<const float4*>(sbase + sc * 16);
    float fv[16];
    *reinterpret_cast<float4*>(&fv[0]) = p4[0];
    *reinterpret_cast<float4*>(&fv[4]) = p4[1];
    *reinterpret_cast<float4*>(&fv[8]) = p4[2];
    *reinterpret_cast<float4*>(&fv[12]) = p4[3];
    ushort8 w0, w1;
#pragma unroll
    for (int j = 0; j < 8; ++j) {
      w0[j] = f2bf(fv[j]);
      w1[j] = f2bf(fv[8 + j]);
    }
    *reinterpret_cast<ushort8*>(&lds[0][wbase + s0]) = w0;
    *reinterpret_cast<ushort8*>(&lds[0][wbase + s1]) = w1;
  }
  __syncthreads();

#pragma unroll
  for (int ks = 0; ks < 4; ++ks) {
    const int cc = ks & 1;

    // B-frags for this step (L2-hot)
    bf16x8 bfr[2][4];
#pragma unroll
    for (int kk = 0; kk < 2; ++kk) {
      const int kc32 = ks * 2 + kk;
#pragma unroll
      for (int fn = 0; fn < 4; ++fn) {
        const int F = wn * 4 + fn;
        bfr[kk][fn] = __builtin_bit_cast(
            bf16x8, *reinterpret_cast<const ushort8*>(
                        BpEe + ((size_t)(kc32 * 16 + F) * 64 + lane) * 8));
      }
    }

    float4 nf0, nf1, nf2, nf3;
    if (ks + 1 < 4) {
      const float4* p4 = reinterpret_cast<const float4*>(sbase + (ks + 1) * 64 + sc * 16);
      nf0 = p4[0];
      nf1 = p4[1];
      nf2 = p4[2];
      nf3 = p4[3];
    }

#pragma unroll
    for (int kk = 0; kk < 2; ++kk) {
      bf16x8 a[4];
#pragma unroll
      for (int fm = 0; fm < 4; ++fm) {
        int r = wm * 64 + fm * 16 + lr;
        int slot = (kk * 4 + q) ^ (r & 7);
        a[fm] = __builtin_bit_cast(
            bf16x8, *reinterpret_cast<const ushort8*>(&lds[cc][r * 64 + slot * 8]));
      }
#pragma unroll
      for (int fm = 0; fm < 4; ++fm)
#pragma unroll
        for (int fn = 0; fn < 4; ++fn)
          acc[fm][fn] = __builtin_amdgcn_mfma_f32_16x16x32_bf16(
              a[fm], bfr[kk][fn], acc[fm][fn], 0, 0, 0);
    }

    if (ks + 1 < 4) {
      float fv[16];
      *reinterpret_cast<float4*>(&fv[0]) = nf0;
      *reinterpret_cast<float4*>(&fv[4]) = nf1;
      *reinterpret_cast<float4*>(&fv[8]) = nf2;
      *reinterpret_cast<float4*>(&fv[12]) = nf3;
      ushort8 w0, w1;
#pragma unroll
      for (int j = 0; j < 8; ++j) {
        w0[j] = f2bf(fv[j]);
        w1[j] = f2bf(fv[8 + j]);
      }
      *reinterpret_cast<ushort8*>(&lds[cc ^ 1][wbase + s0]) = w0;
      *reinterpret_cast<ushort8*>(&lds[cc ^ 1][wbase + s1]) = w1;
      __syncthreads();
    }
  }

  // epilogue: D mapping col = lr, row = q*4 + i
  float bcol[4];
#pragma unroll
  for (int fn = 0; fn < 4; ++fn) bcol[fn] = ce[wn * 64 + fn * 16 + lr];
  float cs[4] = {0.f, 0.f, 0.f, 0.f};

#pragma unroll
  for (int fm = 0; fm < 4; ++fm) {
    int rb = row0 + wm * 64 + fm * 16 + q * 4;
#pragma unroll
    for (int i = 0; i < 4; ++i) {
      int gr = rb + i;
      if (gr < E_CNT) {
        int snd = senders[gr], rcv = receivers[gr];
        us4 ps = *reinterpret_cast<const us4*>(Ps + (size_t)snd * 256 + wn * 64 + lr * 4);
        us4 pr = *reinterpret_cast<const us4*>(Pr + (size_t)rcv * 256 + wn * 64 + lr * 4);
#pragma unroll
        for (int fn = 0; fn < 4; ++fn) {
          int col = wn * 64 + fn * 16 + lr;
          float v = fmaxf(acc[fm][fn][i] + bcol[fn] + bf2f(ps[fn]) + bf2f(pr[fn]), 0.0f);
          cs[fn] += v;
          __builtin_nontemporal_store(v, &out0[(size_t)gr * 256 + col]);
          atomicAdd(agg + (size_t)rcv * 256 + col, v);
        }
      }
    }
  }

  // fused colsum -> partE
  float* csum = reinterpret_cast<float*>(&lds[0][0]);
  __syncthreads();
  if (tid < 256) csum[tid] = 0.f;
  __syncthreads();
#pragma unroll
  for (int fn = 0; fn < 4; ++fn) atomicAdd(&csum[wn * 64 + fn * 16 + lr], cs[fn]);
  __syncthreads();
  if (tid < 256)
    atomicAdd(&partE[(size_t)(blockIdx.x & (CS_PARTS - 1)) * 256 + tid], csum[tid]);
}

// ---------- dispatch 4: node GEMM K=512 (agg | nodes) + esum reduce ----------
__global__ __launch_bounds__(512, 2) void node_gemm(
    const float* __restrict__ agg, const float* __restrict__ nodes,
    const unsigned short* __restrict__ BpN, const float* __restrict__ cn,
    const float* __restrict__ partE, float* __restrict__ esum,
    float* __restrict__ out1, float* __restrict__ partN, int nbN) {
  if (blockIdx.x >= nbN) {
    int c = threadIdx.x;
    if (c < 256) {
      float s = 0.f;
      for (int p = 0; p < CS_PARTS; ++p) s += partE[(size_t)p * 256 + c];
      esum[c] = s;
    }
    return;
  }
  __shared__ unsigned short lds[2][128 * 64];

  const int tid = threadIdx.x;
  const int lane = tid & 63;
  const int wave = tid >> 6;
  const int wm = wave >> 2;
  const int wn = wave & 3;
  const int q = lane >> 4;
  const int lr = lane & 15;
  const int row0 = blockIdx.x * 128;

  const int sr = tid >> 2;
  const int sc = tid & 3;
  int er = row0 + sr;
  if (er > N_CNT - 1) er = N_CNT - 1;
  const float* sbase[2];
  sbase[0] = agg + (size_t)er * 256;
  sbase[1] = nodes + (size_t)er * 256;

  const int swz = sr & 7;
  const int wbase = sr * 64;
  const int s0 = ((sc * 2) ^ swz) * 8;
  const int s1 = ((sc * 2 + 1) ^ swz) * 8;

  f32x4 acc[4][4] = {};

  {
    const float4* p4 = reinterpret_cast<const float4*>(sbase[0] + sc * 16);
    float fv[16];
    *reinterpret_cast<float4*>(&fv[0]) = p4[0];
    *reinterpret_cast<float4*>(&fv[4]) = p4[1];
    *reinterpret_cast<float4*>(&fv[8]) = p4[2];
    *reinterpret_cast<float4*>(&fv[12]) = p4[3];
    ushort8 w0, w1;
#pragma unroll
    for (int j = 0; j < 8; ++j) {
      w0[j] = f2bf(fv[j]);
      w1[j] = f2bf(fv[8 + j]);
    }
    *reinterpret_cast<ushort8*>(&lds[0][wbase + s0]) = w0;
    *reinterpret_cast<ushort8*>(&lds[0][wbase + s1]) = w1;
  }
  __syncthreads();

#pragma unroll
  for (int ks = 0; ks < 8; ++ks) {
    const int cc = ks & 1;

    bf16x8 bfr[2][4];
#pragma unroll
    for (int kk = 0; kk < 2; ++kk) {
      const int kc32 = ks * 2 + kk;
#pragma unroll
      for (int fn = 0; fn < 4; ++fn) {
        const int F = wn * 4 + fn;
        bfr[kk][fn] = __builtin_bit_cast(
            bf16x8, *reinterpret_cast<const ushort8*>(
                        BpN + ((size_t)(kc32 * 16 + F) * 64 + lane) * 8));
      }
    }

    float4 nf0, nf1, nf2, nf3;
    if (ks + 1 < 8) {
      const float4* p4 = reinterpret_cast<const float4*>(
          sbase[(ks + 1) >> 2] + ((ks + 1) & 3) * 64 + sc * 16);
      nf0 = p4[0];
      nf1 = p4[1];
      nf2 = p4[2];
      nf3 = p4[3];
    }

#pragma unroll
    for (int kk = 0; kk < 2; ++kk) {
      bf16x8 a[4];
#pragma unroll
      for (int fm = 0; fm < 4; ++fm) {
        int r = wm * 64 + fm * 16 + lr;
        int slot = (kk * 4 + q) ^ (r & 7);
        a[fm] = __builtin_bit_cast(
            bf16x8, *reinterpret_cast<const ushort8*>(&lds[cc][r * 64 + slot * 8]));
      }
#pragma unroll
      for (int fm = 0; fm < 4; ++fm)
#pragma unroll
        for (int fn = 0; fn < 4; ++fn)
          acc[fm][fn] = __builtin_amdgcn_mfma_f32_16x16x32_bf16(
              a[fm], bfr[kk][fn], acc[fm][fn], 0, 0, 0);
    }

    if (ks + 1 < 8) {
      float fv[16];
      *reinterpret_cast<float4*>(&fv[0]) = nf0;
      *reinterpret_cast<float4*>(&fv[4]) = nf1;
      *reinterpret_cast<float4*>(&fv[8]) = nf2;
      *reinterpret_cast<float4*>(&fv[12]) = nf3;
      ushort8 w0, w1;
#pragma unroll
      for (int j = 0; j < 8; ++j) {
        w0[j] = f2bf(fv[j]);
        w1[j] = f2bf(fv[8 + j]);
      }
      *reinterpret_cast<ushort8*>(&lds[cc ^ 1][wbase + s0]) = w0;
      *reinterpret_cast<ushort8*>(&lds[cc ^ 1][wbase + s1]) = w1;
      __syncthreads();
    }
  }

  float bcol[4];
#pragma unroll
  for (int fn = 0; fn < 4; ++fn) bcol[fn] = cn[wn * 64 + fn * 16 + lr];
  float cs[4] = {0.f, 0.f, 0.f, 0.f};

#pragma unroll
  for (int fm = 0; fm < 4; ++fm) {
    int rb = row0 + wm * 64 + fm * 16 + q * 4;
#pragma unroll
    for (int i = 0; i < 4; ++i) {
      int gr = rb + i;
      if (gr < N_CNT) {
#pragma unroll
        for (int fn = 0; fn < 4; ++fn) {
          int col = wn * 64 + fn * 16 + lr;
          float v = fmaxf(acc[fm][fn][i] + bcol[fn], 0.0f);
          cs[fn] += v;
          out1[(size_t)gr * 256 + col] = v;
        }
      }
    }
  }

  float* csum = reinterpret_cast<float*>(&lds[0][0]);
  __syncthreads();
  if (tid < 256) csum[tid] = 0.f;
  __syncthreads();
#pragma unroll
  for (int fn = 0; fn < 4; ++fn) atomicAdd(&csum[wn * 64 + fn * 16 + lr], cs[fn]);
  __syncthreads();
  if (tid < 256)
    atomicAdd(&partN[(size_t)(blockIdx.x & (CS_PARTS - 1)) * 256 + tid], csum[tid]);
}

// ---------- dispatch 5: nsum reduce + global MLP ----------
__global__ void finalize(const float* __restrict__ partN, const float* __restrict__ esum,
                         const float* __restrict__ gl, const float* __restrict__ Wg,
                         const float* __restrict__ bg, float* __restrict__ out2) {
  __shared__ float ns[256];
  __shared__ float red[512];
  int t = threadIdx.x;  // 512
  if (t < 256) {
    float s = 0.f;
    for (int p = 0; p < CS_PARTS; ++p) s += partN[(size_t)p * 256 + t];
    ns[t] = s;
  }
  __syncthreads();
  int g = t & 127;
  int kg = t >> 7;
  float acc = 0.f;
  for (int k = kg; k < 640; k += 4) {
    float x = (k < 256) ? esum[k] : (k < 512 ? ns[k - 256] : gl[k - 512]);
    acc += x * Wg[(size_t)k * 128 + g];
  }
  red[t] = acc;
  __syncthreads();
  if (kg == 0) {
    float r = red[g] + red[128 + g] + red[256 + g] + red[384 + g] + bg[g];
    out2[g] = fmaxf(r, 0.f);
  }
}

extern "C" void kernel_launch(void* const* d_in, const int* in_sizes, int n_in,
                              void* d_out, int out_size, void* d_ws, size_t ws_size,
                              hipStream_t stream) {
  const float* nodes = (const float*)d_in[0];
  const float* edges = (const float*)d_in[1];
  const float* gl = (const float*)d_in[2];
  const int* senders = (const int*)d_in[3];
  const int* receivers = (const int*)d_in[4];
  const float* We = (const float*)d_in[5];
  const float* be = (const float*)d_in[6];
  const float* Wn = (const float*)d_in[7];
  const float* bn = (const float*)d_in[8];
  const float* Wg = (const float*)d_in[9];
  const float* bg = (const float*)d_in[10];

  float* out0 = (float*)d_out;               // new_edges [200000,256]
  float* out1 = out0 + (size_t)E_CNT * 256;  // new_nodes [50000,256]
  float* out2 = out1 + (size_t)N_CNT * 256;  // new_globals [128]

  // agg (f32) lives in out1's slot during the edge phase; the node kernel
  // reads agg[row] and overwrites out1[row] for the same rows only.
  float* agg = out1;

  char* ws = (char*)d_ws;
  size_t o = 0;
  float* partE = (float*)(ws + o);                  o += CS_PARTS * 256 * 4;
  float* partN = (float*)(ws + o);                  o += CS_PARTS * 256 * 4;
  size_t zeroBytes = o;  // partE + partN in one memset
  unsigned short* Ps = (unsigned short*)(ws + o);   o += (size_t)N_CNT * 256 * 2;
  unsigned short* Pr = (unsigned short*)(ws + o);   o += (size_t)N_CNT * 256 * 2;
  unsigned short* BpEe = (unsigned short*)(ws + o); o += 131072;
  unsigned short* BpPs = (unsigned short*)(ws + o); o += 131072;
  unsigned short* BpPr = (unsigned short*)(ws + o); o += 131072;
  unsigned short* BpN = (unsigned short*)(ws + o);  o += 262144;  // K=512
  float* ce = (float*)(ws + o);                     o += 1024;
  float* cn = (float*)(ws + o);                     o += 1024;
  float* esum = (float*)(ws + o);                   o += 1024;

  hipMemsetAsync(ws, 0, zeroBytes, stream);
  hipMemsetAsync(agg, 0, (size_t)N_CNT * 256 * 4, stream);

  prep_all<<<162, 256, 0, stream>>>(We, be, Wn, bn, gl, BpEe, BpPs, BpPr, BpN, ce, cn);

  proj2<<<(N_CNT + 63) / 64, 512, 0, stream>>>(nodes, BpPs, BpPr, Ps, Pr);

  edge_gemm<<<(E_CNT + 127) / 128, 512, 0, stream>>>(
      edges, BpEe, Ps, Pr, ce, senders, receivers, out0, agg, partE);

  const int nbN = (N_CNT + 127) / 128;  // 391
  node_gemm<<<nbN + 1, 512, 0, stream>>>(agg, nodes, BpN, cn, partE, esum, out1,
                                         partN, nbN);

  finalize<<<1, 512, 0, stream>>>(partN, esum, gl, Wg, bg, out2);
}